// Round 7
// baseline (164.699 us; speedup 1.0000x reference)
//
#include <hip/hip_runtime.h>
#include <hip/hip_bf16.h>

typedef __attribute__((ext_vector_type(8))) __bf16 bf16x8;
typedef __attribute__((ext_vector_type(4))) float f32x4;

#define BATCH   1048576
#define DISTIL  128
#define CLASSES 64
#define NWAVES  4096          // 1024 blocks x 4 waves (launch must match)
#define NTILES  (BATCH / 16)  // 65536
#define TPW     16            // tiles per wave, exact

// D = W^T * z^T (transposed), 16x16x32 bf16 MFMA, W fragments in LDS (16 KB),
// z register-double-buffered. Round 7 change: CONTIGUOUS tile assignment —
// wave g owns tiles [16g, 16g+16), so each wave performs a linear 128-KB read
// scan and 64-KB write scan (DRAM row-buffer locality across bursts) instead
// of 32-MB jumps between tiles. Everything else identical to round 6.
//  - k-PERMUTATION: within an MFMA, k is a label; A and B just must agree.
//    phys_k(lhi,kk,j) = 32*kk + 16*(j>>2) + 4*lhi + (j&3). W is prepacked in
//    this order, so each z-load instruction reads row*512B + lhi*16 + p*64:
//    16 rows x one FULL 64-B sector -> sector-perfect.
//  - Fragment roles: A=W-frag -> D[class][batch]; lane l holds
//    out[batch=rowbase+(l&15)][class = n*16 + (l>>4)*4 + j] -> dwordx4 stores.

#define PREFETCH(buf, t) do {                                                  \
    const float* zr_ = z + ((t) * 16 + l15) * (long)DISTIL + lhi * 4;          \
    _Pragma("unroll")                                                          \
    for (int p = 0; p < 8; ++p)                                                \
        buf[p] = __builtin_nontemporal_load((const f32x4*)(zr_ + p * 16));     \
} while (0)

#define COMPUTE(buf, t) do {                                                   \
    int foff_ = 0;                                                             \
    asm volatile("" : "+v"(foff_));    /* opaque 0: blocks cross-tile CSE */   \
    f32x4 acc0 = *(const f32x4*)(blds +  0 + lhi * 4 + foff_);                 \
    f32x4 acc1 = *(const f32x4*)(blds + 16 + lhi * 4 + foff_);                 \
    f32x4 acc2 = *(const f32x4*)(blds + 32 + lhi * 4 + foff_);                 \
    f32x4 acc3 = *(const f32x4*)(blds + 48 + lhi * 4 + foff_);                 \
    _Pragma("unroll")                                                          \
    for (int kk = 0; kk < 4; ++kk) {                                           \
        f32x4 x0_ = buf[2 * kk], x1_ = buf[2 * kk + 1];                        \
        bf16x8 a_;                                                             \
        _Pragma("unroll")                                                      \
        for (int j = 0; j < 4; ++j) {                                          \
            a_[j]     = (__bf16)x0_[j];                                        \
            a_[4 + j] = (__bf16)x1_[j];                                        \
        }                                                                      \
        bf16x8 b0_ = wf[ 0 + kk + foff_][lane];                                \
        bf16x8 b1_ = wf[ 4 + kk + foff_][lane];                                \
        bf16x8 b2_ = wf[ 8 + kk + foff_][lane];                                \
        bf16x8 b3_ = wf[12 + kk + foff_][lane];                                \
        acc0 = __builtin_amdgcn_mfma_f32_16x16x32_bf16(b0_, a_, acc0, 0, 0, 0);\
        acc1 = __builtin_amdgcn_mfma_f32_16x16x32_bf16(b1_, a_, acc1, 0, 0, 0);\
        acc2 = __builtin_amdgcn_mfma_f32_16x16x32_bf16(b2_, a_, acc2, 0, 0, 0);\
        acc3 = __builtin_amdgcn_mfma_f32_16x16x32_bf16(b3_, a_, acc3, 0, 0, 0);\
    }                                                                          \
    float* orow_ = out + ((t) * 16 + l15) * (long)CLASSES + lhi * 4;           \
    *(f32x4*)(orow_)      = acc0;                                              \
    *(f32x4*)(orow_ + 16) = acc1;                                              \
    *(f32x4*)(orow_ + 32) = acc2;                                              \
    *(f32x4*)(orow_ + 48) = acc3;                                              \
} while (0)

__global__ __launch_bounds__(256, 4) void linclass_kernel(
    const float* __restrict__ z, const float* __restrict__ W,
    const float* __restrict__ bias, float* __restrict__ out)
{
    const int lane = threadIdx.x & 63;
    const int w    = threadIdx.x >> 6;   // wave id 0..3
    const int l15  = lane & 15;
    const int lhi  = lane >> 4;          // 0..3

    // LDS: W fragments in permuted-k order + bias
    __shared__ __align__(16) bf16x8 wf[16][64];   // frag f = n*4+kk
    __shared__ __align__(16) float  blds[64];

    // prepack: wave w packs the 4 kk-frags for class group n == w
#pragma unroll
    for (int kk = 0; kk < 4; ++kk) {
        bf16x8 fr;
#pragma unroll
        for (int j = 0; j < 8; ++j) {
            const int phys = 32 * kk + ((j >> 2) << 4) + lhi * 4 + (j & 3);
            fr[j] = (__bf16)W[phys * CLASSES + w * 16 + l15];
        }
        wf[w * 4 + kk][lane] = fr;
    }
    if (threadIdx.x < 64) blds[threadIdx.x] = bias[threadIdx.x];
    __syncthreads();

    const long gwave = (long)blockIdx.x * 4 + w;   // 0..4095
    const long tbase = gwave * TPW;                // contiguous 16-tile span

    // 16 tiles per wave, register double-buffered z prefetch, linear scan
    f32x4 bufA[8], bufB[8];
    PREFETCH(bufA, tbase);
#pragma unroll
    for (int i = 0; i < TPW; i += 2) {
        const long ta = tbase + i;
        const long tb = tbase + i + 1;
        PREFETCH(bufB, tb);
        COMPUTE(bufA, ta);
        if (i + 2 < TPW) PREFETCH(bufA, tbase + i + 2);
        COMPUTE(bufB, tb);
    }
}

extern "C" void kernel_launch(void* const* d_in, const int* in_sizes, int n_in,
                              void* d_out, int out_size, void* d_ws, size_t ws_size,
                              hipStream_t stream) {
    const float* z    = (const float*)d_in[0];   // [1048576, 128]
    const float* W    = (const float*)d_in[1];   // [128, 64]
    const float* bias = (const float*)d_in[2];   // [64]
    float* out        = (float*)d_out;           // [1048576, 64]

    dim3 grid(1024), block(256);                 // 4096 waves == NWAVES
    linclass_kernel<<<grid, block, 0, stream>>>(z, W, bias, out);
}

// Round 8
// 149.956 us; speedup vs baseline: 1.0983x; 1.0983x over previous
//
#include <hip/hip_runtime.h>
#include <hip/hip_bf16.h>

typedef __attribute__((ext_vector_type(8))) __bf16 bf16x8;
typedef __attribute__((ext_vector_type(4))) float f32x4;

#define BATCH   1048576
#define DISTIL  128
#define CLASSES 64
#define NWAVES  4096          // 1024 blocks x 4 waves (launch must match)
#define NTILES  (BATCH / 16)  // 65536
#define TPW     16            // tiles per wave, exact

// D = W^T * z^T (transposed), 16x16x32 bf16 MFMA, W fragments in LDS (16 KB),
// z register-double-buffered, interleaved tile mapping (contiguous regressed R7;
// nt loads null R6). Round 8 change: PROLOGUE OVERLAP — both initial tile
// prefetches issue BEFORE the W-prepack + syncthreads, so the GPU-wide
// prologue bubble (~2-5 us of HBM idle while all 1024 co-resident blocks
// chase W-load latency) is filled with z reads. Loop rotated so each buffer
// is re-prefetched right after it is consumed.
//  - k-PERMUTATION: within an MFMA, k is a label; A and B just must agree.
//    phys_k(lhi,kk,j) = 32*kk + 16*(j>>2) + 4*lhi + (j&3). W prepacked in this
//    order so each z-load instruction reads full 64-B sectors.
//  - Fragment roles: A=W-frag -> D[class][batch]; lane l holds
//    out[batch=rowbase+(l&15)][class = n*16 + (l>>4)*4 + j] -> dwordx4 stores.

#define PREFETCH(buf, t) do {                                                  \
    const float* zr_ = z + ((t) * 16 + l15) * (long)DISTIL + lhi * 4;          \
    _Pragma("unroll")                                                          \
    for (int p = 0; p < 8; ++p) buf[p] = *(const f32x4*)(zr_ + p * 16);        \
} while (0)

#define COMPUTE(buf, t) do {                                                   \
    int foff_ = 0;                                                             \
    asm volatile("" : "+v"(foff_));    /* opaque 0: blocks cross-tile CSE */   \
    f32x4 acc0 = *(const f32x4*)(blds +  0 + lhi * 4 + foff_);                 \
    f32x4 acc1 = *(const f32x4*)(blds + 16 + lhi * 4 + foff_);                 \
    f32x4 acc2 = *(const f32x4*)(blds + 32 + lhi * 4 + foff_);                 \
    f32x4 acc3 = *(const f32x4*)(blds + 48 + lhi * 4 + foff_);                 \
    _Pragma("unroll")                                                          \
    for (int kk = 0; kk < 4; ++kk) {                                           \
        f32x4 x0_ = buf[2 * kk], x1_ = buf[2 * kk + 1];                        \
        bf16x8 a_;                                                             \
        _Pragma("unroll")                                                      \
        for (int j = 0; j < 4; ++j) {                                          \
            a_[j]     = (__bf16)x0_[j];                                        \
            a_[4 + j] = (__bf16)x1_[j];                                        \
        }                                                                      \
        bf16x8 b0_ = wf[ 0 + kk + foff_][lane];                                \
        bf16x8 b1_ = wf[ 4 + kk + foff_][lane];                                \
        bf16x8 b2_ = wf[ 8 + kk + foff_][lane];                                \
        bf16x8 b3_ = wf[12 + kk + foff_][lane];                                \
        acc0 = __builtin_amdgcn_mfma_f32_16x16x32_bf16(b0_, a_, acc0, 0, 0, 0);\
        acc1 = __builtin_amdgcn_mfma_f32_16x16x32_bf16(b1_, a_, acc1, 0, 0, 0);\
        acc2 = __builtin_amdgcn_mfma_f32_16x16x32_bf16(b2_, a_, acc2, 0, 0, 0);\
        acc3 = __builtin_amdgcn_mfma_f32_16x16x32_bf16(b3_, a_, acc3, 0, 0, 0);\
    }                                                                          \
    float* orow_ = out + ((t) * 16 + l15) * (long)CLASSES + lhi * 4;           \
    *(f32x4*)(orow_)      = acc0;                                              \
    *(f32x4*)(orow_ + 16) = acc1;                                              \
    *(f32x4*)(orow_ + 32) = acc2;                                              \
    *(f32x4*)(orow_ + 48) = acc3;                                              \
} while (0)

__global__ __launch_bounds__(256, 4) void linclass_kernel(
    const float* __restrict__ z, const float* __restrict__ W,
    const float* __restrict__ bias, float* __restrict__ out)
{
    const int lane = threadIdx.x & 63;
    const int w    = threadIdx.x >> 6;   // wave id 0..3
    const int l15  = lane & 15;
    const int lhi  = lane >> 4;          // 0..3

    __shared__ __align__(16) bf16x8 wf[16][64];   // frag f = n*4+kk
    __shared__ __align__(16) float  blds[64];

    const long gwave = (long)blockIdx.x * 4 + w;   // 0..4095

    // ---- issue BOTH initial tile prefetches first: z reads fill the
    //      prologue bubble while the W-prepack latency chains resolve ----
    f32x4 bufA[8], bufB[8];
    PREFETCH(bufA, gwave);
    PREFETCH(bufB, gwave + NWAVES);

    // ---- prepack W fragments (permuted-k order) + bias, then sync ----
#pragma unroll
    for (int kk = 0; kk < 4; ++kk) {
        bf16x8 fr;
#pragma unroll
        for (int j = 0; j < 8; ++j) {
            const int phys = 32 * kk + ((j >> 2) << 4) + lhi * 4 + (j & 3);
            fr[j] = (__bf16)W[phys * CLASSES + w * 16 + l15];
        }
        wf[w * 4 + kk][lane] = fr;
    }
    if (threadIdx.x < 64) blds[threadIdx.x] = bias[threadIdx.x];
    __syncthreads();

    // ---- 16 tiles per wave, rotated double-buffer loop ----
#pragma unroll
    for (int i = 0; i < TPW; i += 2) {
        const long ta = gwave + (long)i * NWAVES;
        COMPUTE(bufA, ta);
        if (i + 2 < TPW) PREFETCH(bufA, ta + 2 * NWAVES);
        COMPUTE(bufB, ta + NWAVES);
        if (i + 3 < TPW) PREFETCH(bufB, ta + 3 * NWAVES);
    }
}

extern "C" void kernel_launch(void* const* d_in, const int* in_sizes, int n_in,
                              void* d_out, int out_size, void* d_ws, size_t ws_size,
                              hipStream_t stream) {
    const float* z    = (const float*)d_in[0];   // [1048576, 128]
    const float* W    = (const float*)d_in[1];   // [128, 64]
    const float* bias = (const float*)d_in[2];   // [64]
    float* out        = (float*)d_out;           // [1048576, 64]

    dim3 grid(1024), block(256);                 // 4096 waves == NWAVES
    linclass_kernel<<<grid, block, 0, stream>>>(z, W, bias, out);
}